// Round 1
// baseline (6042.599 us; speedup 1.0000x reference)
//
#include <hip/hip_runtime.h>
#include <stdint.h>

#define T_STEPS 512
#define BATCH   512
#define DIN     128
#define HID     256
#define NCLS    1000
#define BBLK    16                 // batch rows per block
#define NBLK    (BATCH/BBLK)       // 32 persistent blocks

typedef __attribute__((ext_vector_type(8))) short  short8;   // 8 x bf16 (MFMA A/B frag)
typedef __attribute__((ext_vector_type(4))) short  short4v;
typedef __attribute__((ext_vector_type(4))) float  f32x4;    // MFMA C/D frag

__device__ __forceinline__ short f2bf(float f){
  uint32_t u = __float_as_uint(f);
  uint32_t r = (u + 0x7FFFu + ((u >> 16) & 1u)) >> 16;   // RNE
  return (short)r;
}

// ---------------------------------------------------------------------------
// Pack W_ih (768x128) and W_hh (768x256) fp32 -> bf16 in fragment-friendly
// layout: P[kb][j][e] = W[j][kb*8+e]  (kb = k/8). A lane's B-fragment for
// (k-tile kt, group g=lane>>4, col j) is then the 16B run P[(kt*4+g)][j][0..7],
// fully coalesced across the 16 lanes of a group (consecutive j).
// ---------------------------------------------------------------------------
__global__ __launch_bounds__(256) void pack_weights(
    const float* __restrict__ Wih, const float* __restrict__ Whh,
    short* __restrict__ PIH, short* __restrict__ PHH)
{
  int idx = blockIdx.x * 256 + threadIdx.x;   // over 16*768 + 32*768 = 36864 groups
  if (idx >= 48*768) return;
  const float* src; short* dst;
  if (idx < 16*768){
    int kb = idx / 768, j = idx - kb*768;
    src = Wih + (size_t)j*DIN + kb*8;
    dst = PIH + (size_t)idx*8;
  } else {
    int i2 = idx - 16*768;
    int kb = i2 / 768, j = i2 - kb*768;
    src = Whh + (size_t)j*HID + kb*8;
    dst = PHH + (size_t)i2*8;
  }
  short8 v;
  #pragma unroll
  for (int e=0;e<8;e++) v[e] = f2bf(src[e]);
  *(short8*)dst = v;
}

// ---------------------------------------------------------------------------
// Persistent GRU scan. Grid = 32 blocks x 512 threads (8 waves). Block owns 16
// batch rows; h lives in registers (fp32 master) + LDS bf16 copy for MFMA.
// Per step: unified A-tile [16][392] bf16 (k 0..127 = x_t, 128..383 = h),
// each wave computes 8 N-tiles (2 per section r/z/i_n/h_n), K-loop kt=0..11.
// Pre-activations land in LDS G[16][1028] (cols: r|z|i_n|h_n), then all 512
// threads do the gate math.  2 barriers per step, no grid sync ever.
// ---------------------------------------------------------------------------
__global__ __launch_bounds__(512, 1) void gru_scan(
    const float* __restrict__ x,    const float* __restrict__ b_ih,
    const float* __restrict__ b_hh, const float* __restrict__ mask,
    const short* __restrict__ PIH,  const short* __restrict__ PHH,
    float* __restrict__ HFIN)
{
  __shared__ short Asm[16*392];        // 12.5 KB  (row stride 392 bf16 = 49x16B)
  __shared__ float G[16*1028];         // 65.8 KB
  __shared__ float bsr[256], bsz[256], bin_[256], bhn[256];

  const int tid = threadIdx.x;
  const int b0  = blockIdx.x * BBLK;
  const int w   = tid >> 6;            // wave 0..7
  const int l   = tid & 63;
  const int c   = l & 15;              // MFMA A-row / B-col / C-col lane index
  const int g   = l >> 4;              // k-group

  // one-time staging: fused biases, zero h
  if (tid < 256){
    int u = tid;
    bsr[u]  = b_ih[u]       + b_hh[u];
    bsz[u]  = b_ih[256+u]   + b_hh[256+u];
    bin_[u] = b_ih[512+u];
    bhn[u]  = b_hh[512+u];
  }
  for (int i=tid; i<16*392; i+=512) Asm[i] = 0;   // zeros h part (and x part)

  float hreg[8];                       // this thread's h values: (b = bhalf+2*rep, u = uu)
  #pragma unroll
  for (int r=0;r<8;r++) hreg[r] = 0.f;
  const int uu    = tid & 255;
  const int bhalf = tid >> 8;          // 0/1

  // per-wave tile columns: q=0..7 -> section s=q&3 (r,z,i_n,h_n), tile (w + 8*(q>>2))
  int colq[8], jq[8];
  #pragma unroll
  for (int q=0;q<8;q++){
    int s = q & 3;
    int off = (w + 8*(q>>2))*16 + c;
    colq[q] = s*256 + off;                       // column in G (0..1023)
    jq[q]   = (s==3) ? (512 + off) : colq[q];    // row in W (h_n maps to W rows 512..767)
  }

  __syncthreads();

  for (int t=0; t<T_STEPS; ++t){
    // ---- stage x_t -> A[.][0..127] (bf16), 1 float4 per thread ----
    {
      int d4   = tid & 31;
      int brow = tid >> 5;
      f32x4 xv = *(const f32x4*)(x + ((size_t)(b0+brow)*T_STEPS + t)*DIN + d4*4);
      short4v sv;
      #pragma unroll
      for (int e=0;e<4;e++) sv[e] = f2bf(xv[e]);
      *(short4v*)&Asm[brow*392 + d4*4] = sv;
    }
    __syncthreads();                   // A ready; prev step's G fully consumed

    // ---- fused GEMM: acc[q] over kt (kt<4: x@W_ih, kt>=4: h@W_hh) ----
    f32x4 acc[8] = {};
    #pragma unroll
    for (int kt=0; kt<12; ++kt){
      const short8 afrag = *(const short8*)&Asm[c*392 + kt*32 + g*8];
      const short* wbase = (kt < 4) ? (PIH + ((size_t)(kt*4+g)*768)*8)
                                    : (PHH + ((size_t)((kt-4)*4+g)*768)*8);
      #pragma unroll
      for (int q=0;q<8;q++){
        const int s = q & 3;
        if (s==2 && kt>=4) continue;   // i_n: x-part only
        if (s==3 && kt< 4) continue;   // h_n: h-part only
        short8 bfrag = *(const short8*)(wbase + (size_t)jq[q]*8);
        acc[q] = __builtin_amdgcn_mfma_f32_16x16x32_bf16(afrag, bfrag, acc[q], 0,0,0);
      }
    }
    // ---- spill pre-activations to G (C/D layout: col=l&15, row=g*4+i) ----
    #pragma unroll
    for (int q=0;q<8;q++){
      #pragma unroll
      for (int i=0;i<4;i++) G[(g*4+i)*1028 + colq[q]] = acc[q][i];
    }
    __syncthreads();                   // G ready

    // ---- gate math: 512 threads x 8 (b,u) pairs ----
    #pragma unroll
    for (int rep=0; rep<8; ++rep){
      const int bb = bhalf + rep*2;
      float gr  = G[bb*1028 +        uu] + bsr[uu];
      float gz  = G[bb*1028 + 256  + uu] + bsz[uu];
      float gin = G[bb*1028 + 512  + uu] + bin_[uu];
      float ghn = G[bb*1028 + 768  + uu] + bhn[uu];
      float r = 1.f/(1.f + __expf(-gr));
      float z = 1.f/(1.f + __expf(-gz));
      float e2 = __expf(2.f*(gin + r*ghn));
      float n  = 1.f - 2.f/(e2 + 1.f);           // tanh, saturates correctly at +-inf
      float m  = mask[((size_t)t*BATCH + (b0+bb))*HID + uu];
      float hn = ((1.f - z)*n + z*hreg[rep]) * m;
      hreg[rep] = hn;
      Asm[bb*392 + 128 + uu] = f2bf(hn);         // bf16 copy for next step's MFMA
    }
    // next iteration's top barrier separates these h writes from the GEMM reads
  }

  #pragma unroll
  for (int rep=0; rep<8; ++rep)
    HFIN[(size_t)(b0 + bhalf + rep*2)*HID + uu] = hreg[rep];
}

// ---------------------------------------------------------------------------
// out = h @ W_out^T + b_out   (512x256 @ 256x1000), fp32 vector — tiny.
// Block: 16 b-rows x 64 c-cols, h staged in LDS (broadcast reads).
// ---------------------------------------------------------------------------
__global__ __launch_bounds__(256) void out_gemm(
    const float* __restrict__ Hf, const float* __restrict__ Wout,
    const float* __restrict__ bout, float* __restrict__ out)
{
  __shared__ float hl[16*256];
  const int bb0 = (blockIdx.x >> 4) * 16;   // 32 b-tiles
  const int cc0 = (blockIdx.x & 15) * 64;   // 16 c-tiles
  for (int i=threadIdx.x; i<16*256; i+=256) hl[i] = Hf[(size_t)bb0*256 + i];
  __syncthreads();
  const int cc = cc0 + (threadIdx.x & 63);
  const int br = threadIdx.x >> 6;          // 0..3 -> rows br, br+4, br+8, br+12
  if (cc >= NCLS) return;
  const f32x4* wr = (const f32x4*)(Wout + (size_t)cc*HID);
  float a0=0.f, a1=0.f, a2=0.f, a3=0.f;
  #pragma unroll 8
  for (int k4=0;k4<64;k4++){
    f32x4 wv = wr[k4];
    #pragma unroll
    for (int e=0;e<4;e++){
      float we = wv[e]; int k = k4*4+e;
      a0 += hl[(br   )*256+k]*we;
      a1 += hl[(br+ 4)*256+k]*we;
      a2 += hl[(br+ 8)*256+k]*we;
      a3 += hl[(br+12)*256+k]*we;
    }
  }
  float bo = bout[cc];
  out[(size_t)(bb0+br   )*NCLS + cc] = a0 + bo;
  out[(size_t)(bb0+br+ 4)*NCLS + cc] = a1 + bo;
  out[(size_t)(bb0+br+ 8)*NCLS + cc] = a2 + bo;
  out[(size_t)(bb0+br+12)*NCLS + cc] = a3 + bo;
}

// ---------------------------------------------------------------------------
extern "C" void kernel_launch(void* const* d_in, const int* in_sizes, int n_in,
                              void* d_out, int out_size, void* d_ws, size_t ws_size,
                              hipStream_t stream) {
  const float* x     = (const float*)d_in[0];
  const float* W_ih  = (const float*)d_in[1];
  const float* W_hh  = (const float*)d_in[2];
  const float* b_ih  = (const float*)d_in[3];
  const float* b_hh  = (const float*)d_in[4];
  const float* W_out = (const float*)d_in[5];
  const float* b_out = (const float*)d_in[6];
  const float* dmask = (const float*)d_in[7];

  // ws layout: PIH bf16 [16*768*8] (192KB) | PHH bf16 [32*768*8] (384KB) | HFIN f32 (512KB)
  short* PIH  = (short*)d_ws;
  short* PHH  = PIH + (size_t)16*768*8;
  float* HFIN = (float*)((char*)d_ws + 589824);

  pack_weights<<<144, 256, 0, stream>>>(W_ih, W_hh, PIH, PHH);
  gru_scan<<<NBLK, 512, 0, stream>>>(x, b_ih, b_hh, dmask, PIH, PHH, HFIN);
  out_gemm<<<512, 256, 0, stream>>>(HFIN, W_out, b_out, (float*)d_out);
}